// Round 3
// baseline (380.209 us; speedup 1.0000x reference)
//
#include <hip/hip_runtime.h>

// OTTT single step:
//   u_pre  = sig_tau * u + x @ W + b
//   s      = (u_pre >= 1.0)
//   u_new  = u_pre - s
//   a_hat' = sig_tau * a_hat + x
// Outputs concatenated: [s (8192) | u_new (8192) | a_hat_new (8192)], f32.
//
// HBM-bound GEMV: W = 256 MiB f32 read dominates (~40 us floor at 6.7 TB/s).
// R3: slab-streaming gemv — each block reads a fully contiguous 512 KiB slab
// of W (16 complete rows), maximizing DRAM locality. 512 row-chunk partials
// (16 MiB) reduced in 2 stages so the reduction spreads over 512 blocks
// instead of 32 (old finalize was per-CU BW-capped at ~11 us).

#define IN_DIM   8192
#define OUT_DIM  8192
#define COLS4    (OUT_DIM / 4)          // 2048 float4 per row
#define SIG_TAU  0.8807970779778823f    // sigmoid(2.0)
#define V_TH     1.0f

#define ROWS_PB  16                     // rows per gemv block
#define NCH      (IN_DIM / ROWS_PB)     // 512 row-chunks
#define GROUPS   16                     // stage-A groups
#define CH_PER_G (NCH / GROUPS)         // 32 chunks per group
#define TILES    8                      // float4 col-tiles per thread (2048/256)

// grid = 512 blocks (2/CU). Block b reads W rows [16b, 16b+16) in full —
// one contiguous 512 KiB slab — accumulating 8 float4 column tiles/thread.
__global__ __launch_bounds__(256, 2) void gemv_slab(
    const float* __restrict__ W,
    const float* __restrict__ x,
    float* __restrict__ part)
{
    const int row0 = blockIdx.x * ROWS_PB;

    __shared__ float xs[ROWS_PB];
    if (threadIdx.x < ROWS_PB) xs[threadIdx.x] = x[row0 + threadIdx.x];
    __syncthreads();

    float xv[ROWS_PB];
    #pragma unroll
    for (int r = 0; r < ROWS_PB; ++r) xv[r] = xs[r];

    const float4* Wp = (const float4*)W + (size_t)row0 * COLS4 + threadIdx.x;

    float4 acc[TILES];
    #pragma unroll
    for (int t = 0; t < TILES; ++t) acc[t] = make_float4(0.f, 0.f, 0.f, 0.f);

    #pragma unroll 4
    for (int r = 0; r < ROWS_PB; ++r) {
        #pragma unroll
        for (int t = 0; t < TILES; ++t) {
            float4 w = Wp[(size_t)r * COLS4 + t * 256];
            acc[t].x = fmaf(xv[r], w.x, acc[t].x);
            acc[t].y = fmaf(xv[r], w.y, acc[t].y);
            acc[t].z = fmaf(xv[r], w.z, acc[t].z);
            acc[t].w = fmaf(xv[r], w.w, acc[t].w);
        }
    }

    float4* pp = (float4*)part + (size_t)blockIdx.x * COLS4 + threadIdx.x;
    #pragma unroll
    for (int t = 0; t < TILES; ++t) pp[t * 256] = acc[t];
}

// Stage A: grid (32, 16). Block (cx, g) sums chunks [32g, 32g+32) for 256
// columns -> part2[g][col]. 512 blocks streaming 16 MiB, fully coalesced.
__global__ __launch_bounds__(256) void reduce_a(
    const float* __restrict__ part,
    float* __restrict__ part2)
{
    const int col = blockIdx.x * 256 + threadIdx.x;
    const int g   = blockIdx.y;
    const float* p = part + (size_t)g * CH_PER_G * OUT_DIM + col;

    float s = 0.f;
    #pragma unroll
    for (int c = 0; c < CH_PER_G; ++c)
        s += p[(size_t)c * OUT_DIM];

    part2[(size_t)g * OUT_DIM + col] = s;
}

// Stage B: 32 blocks. Sum 16 group-partials (L2-hot 512 KiB) + LIF epilogue.
__global__ __launch_bounds__(256) void finalize_lif2(
    const float* __restrict__ part2,
    const float* __restrict__ b,
    const float* __restrict__ u,
    const float* __restrict__ a_hat,
    const float* __restrict__ x,
    float* __restrict__ out)
{
    const int j = blockIdx.x * 256 + threadIdx.x;

    float sum = 0.f;
    #pragma unroll
    for (int g = 0; g < GROUPS; ++g)
        sum += part2[(size_t)g * OUT_DIM + j];

    const float u_pre = fmaf(SIG_TAU, u[j], sum + b[j]);
    const float s = (u_pre >= V_TH) ? 1.0f : 0.0f;

    out[j]               = s;
    out[OUT_DIM + j]     = u_pre - s * V_TH;
    out[2 * OUT_DIM + j] = fmaf(SIG_TAU, a_hat[j], x[j]);
}

// ---- fallback path (small ws): original column-split gemv + 1-stage finalize
__global__ __launch_bounds__(256) void gemv_partial_gen(
    const float* __restrict__ W,
    const float* __restrict__ x,
    float* __restrict__ part,
    int chunk_rows)
{
    const int col4 = blockIdx.x * 256 + threadIdx.x;
    const int row0 = blockIdx.y * chunk_rows;

    extern __shared__ float xsg[];
    for (int t = threadIdx.x; t < chunk_rows; t += 256)
        xsg[t] = x[row0 + t];
    __syncthreads();

    const float4* Wp = (const float4*)W + (size_t)row0 * COLS4 + col4;
    float4 acc = make_float4(0.f, 0.f, 0.f, 0.f);

    #pragma unroll 8
    for (int r = 0; r < chunk_rows; ++r) {
        float4 w = Wp[(size_t)r * COLS4];
        const float xvv = xsg[r];
        acc.x = fmaf(xvv, w.x, acc.x);
        acc.y = fmaf(xvv, w.y, acc.y);
        acc.z = fmaf(xvv, w.z, acc.z);
        acc.w = fmaf(xvv, w.w, acc.w);
    }

    ((float4*)part)[(size_t)blockIdx.y * COLS4 + col4] = acc;
}

__global__ __launch_bounds__(256) void finalize_lif1(
    const float* __restrict__ part,
    const float* __restrict__ b,
    const float* __restrict__ u,
    const float* __restrict__ a_hat,
    const float* __restrict__ x,
    float* __restrict__ out,
    int nchunks)
{
    const int j = blockIdx.x * 256 + threadIdx.x;
    if (j >= OUT_DIM) return;

    float sum = 0.f;
    #pragma unroll 8
    for (int c = 0; c < nchunks; ++c)
        sum += part[(size_t)c * OUT_DIM + j];

    const float u_pre = fmaf(SIG_TAU, u[j], sum + b[j]);
    const float s = (u_pre >= V_TH) ? 1.0f : 0.0f;

    out[j]               = s;
    out[OUT_DIM + j]     = u_pre - s * V_TH;
    out[2 * OUT_DIM + j] = fmaf(SIG_TAU, a_hat[j], x[j]);
}

extern "C" void kernel_launch(void* const* d_in, const int* in_sizes, int n_in,
                              void* d_out, int out_size, void* d_ws, size_t ws_size,
                              hipStream_t stream)
{
    const float* W     = (const float*)d_in[0];
    const float* b     = (const float*)d_in[1];
    const float* u     = (const float*)d_in[2];
    const float* a_hat = (const float*)d_in[3];
    const float* x     = (const float*)d_in[4];
    float* out = (float*)d_out;

    const size_t part_elems  = (size_t)NCH * OUT_DIM;           // 4 Mi floats
    const size_t part2_elems = (size_t)GROUPS * OUT_DIM;        // 128 Ki floats

    if ((part_elems + part2_elems) * sizeof(float) <= ws_size) {
        float* part  = (float*)d_ws;
        float* part2 = part + part_elems;

        gemv_slab<<<NCH, 256, 0, stream>>>(W, x, part);
        dim3 ga(OUT_DIM / 256, GROUPS);
        reduce_a<<<ga, 256, 0, stream>>>(part, part2);
        finalize_lif2<<<OUT_DIM / 256, 256, 0, stream>>>(part2, b, u, a_hat, x, out);
    } else {
        float* part = (float*)d_ws;
        int nchunks = 128;
        while (nchunks > 1 && (size_t)nchunks * OUT_DIM * sizeof(float) > ws_size)
            nchunks >>= 1;
        const int chunk_rows = IN_DIM / nchunks;
        dim3 grid(OUT_DIM / (4 * 256), nchunks);
        gemv_partial_gen<<<grid, 256, chunk_rows * sizeof(float), stream>>>(W, x, part, chunk_rows);
        finalize_lif1<<<OUT_DIM / 256, 256, 0, stream>>>(part, b, u, a_hat, x, out, nchunks);
    }
}